// Round 16
// baseline (227.016 us; speedup 1.0000x reference)
//
#include <hip/hip_runtime.h>
#include <hip/hip_bf16.h>
#include <hip/hip_fp16.h>
#include <math.h>

typedef __hip_bfloat16 bf16;
typedef unsigned int u32;
typedef unsigned long long u64;
typedef __attribute__((ext_vector_type(8))) short short8;
typedef __attribute__((ext_vector_type(4))) float float4v;

#define T_   4
#define C_   64
#define H_   96
#define W_   96
#define CI_  16
#define HW_  9216
#define NC_  441
#define K_   100
#define HSEL 0x07060302u
#define LSEL 0x05040100u
#define CWS  20    // Cw stride in floats (R15 proven: bank conflicts 4.0M -> 1.67M)

__device__ __forceinline__ float ldbf(const void* p, int i) { return __bfloat162float(((const bf16*)p)[i]); }
__device__ __forceinline__ float ldf (const void* p, int i) { return ((const float*)p)[i]; }

__device__ __forceinline__ unsigned short f2bf(float x) {
    union { float f; u32 u; } a; a.f = x;
    u32 r = a.u + 0x7FFF + ((a.u >> 16) & 1);
    return (unsigned short)(r >> 16);
}
__device__ __forceinline__ float bf2f(unsigned short s) {
    union { u32 u; float f; } a; a.u = ((u32)s) << 16;
    return a.f;
}
__device__ __forceinline__ u32 packbf(float x) {
    unsigned short h = f2bf(x);
    unsigned short l = f2bf(x - bf2f(h));
    return ((u32)h << 16) | (u32)l;
}
__device__ __forceinline__ u32 okey(float f) {
    u32 u = __float_as_uint(f);
    return u ^ ((u & 0x80000000u) ? 0xFFFFFFFFu : 0x80000000u);
}
__device__ __forceinline__ float unokey(u32 k) {
    u32 u = (k & 0x80000000u) ? (k ^ 0x80000000u) : ~k;
    return __uint_as_float(u);
}
__device__ __forceinline__ int cntdim(int x) {
    int c = 0;
#pragma unroll
    for (int pp = 0; pp < 7; pp++) {
        int q = x - pp;
        c += (q >= 0 && q <= 92 && ((q & 3) == 0)) ? 1 : 0;
    }
    if (x == 95) c += 3;
    return c;
}

// per-block dtype vote (fp32 low-mantissa words decode to "insane" bf16 exponents)
__device__ __forceinline__ int detect_flag(const void* vid, int tid, int* sflag) {
    if (tid < 64) {
        unsigned short w = ((const unsigned short*)vid)[tid * 2];
        int e = (w >> 7) & 0xFF;
        int sane = ((e >= 100 && e <= 140) || ((w & 0x7FFF) == 0)) ? 1 : 0;
#pragma unroll
        for (int off = 1; off < 64; off <<= 1) sane += __shfl_xor(sane, off);
        if (tid == 0) *sflag = (sane >= 48) ? 1 : 0;
    }
    __syncthreads();
    return *sflag;
}

// ---------------- conv1x1 x3 + format conversion + ACC zero (R12 proven) ----------------
__global__ __launch_bounds__(256) void conv3_k(const void* vid, const void* gw, const void* gb,
                                               const void* tw, const void* tb, const void* pw,
                                               const void* pb,
                                               u32* __restrict__ B1p, __half* __restrict__ B2h,
                                               u32* __restrict__ B3p, float* __restrict__ ACCb)
{
    __shared__ __align__(16) float w[3120];
    __shared__ int sflag;
    int tid = threadIdx.x;
    int isbf = detect_flag(vid, tid, &sflag);
    for (int i = tid; i < 3120; i += 256) {
        float v;
        if (isbf) {
            if (i < 1024) v = ldbf(gw, i);
            else if (i < 2048) v = ldbf(tw, i - 1024);
            else if (i < 3072) v = ldbf(pw, i - 2048);
            else if (i < 3088) v = ldbf(gb, i - 3072);
            else if (i < 3104) v = ldbf(tb, i - 3088);
            else v = ldbf(pb, i - 3104);
        } else {
            if (i < 1024) v = ldf(gw, i);
            else if (i < 2048) v = ldf(tw, i - 1024);
            else if (i < 3072) v = ldf(pw, i - 2048);
            else if (i < 3088) v = ldf(gb, i - 3072);
            else if (i < 3104) v = ldf(tb, i - 3088);
            else v = ldf(pb, i - 3104);
        }
        int d;
        if (i < 3072) {
            int conv = i >> 10;               // 0,1,2
            int idx  = i & 1023;              // o*64 + c
            int o = idx >> 6, c = idx & 63;
            d = conv * 1024 + c * 16 + o;     // transposed: [conv][c][o]
        } else d = i;
        w[d] = v;
    }
    __syncthreads();

    {
        float2 z = {0.f, 0.f};
        *(float2*)(ACCb + (blockIdx.x * 256 + tid) * 2) = z;   // 1152*256*8B = 2359296 exactly (layout-agnostic)
    }

    int lane32 = tid & 31, og = tid >> 5;      // og in [0,8), 2 channels each
    int g0 = blockIdx.x * 32 + lane32;         // 1152*32 = 36864 exactly
    int t = g0 / HW_, pix = g0 - t * HW_;

    float a1[2], a2[2], a3[2];
#pragma unroll
    for (int k = 0; k < 2; k++) {
        a1[k] = w[3072 + og * 2 + k];
        a2[k] = w[3088 + og * 2 + k];
        a3[k] = w[3104 + og * 2 + k];
    }
    int base = t * C_ * HW_ + pix;
#pragma unroll 16
    for (int c = 0; c < 64; c++) {
        float v = isbf ? ldbf(vid, base + c * HW_) : ldf(vid, base + c * HW_);
        float2 w1 = *(const float2*)&w[c * 16 + og * 2];
        float2 w2 = *(const float2*)&w[1024 + c * 16 + og * 2];
        float2 w3 = *(const float2*)&w[2048 + c * 16 + og * 2];
#pragma unroll
        for (int k = 0; k < 2; k++) {
            a1[k] += v * (&w1.x)[k];
            a2[k] += v * (&w2.x)[k];
            a3[k] += v * (&w3.x)[k];
        }
    }
    int ob = g0 * 16 + og * 2;
    uint2 p1, p3;
    p1.x = packbf(a1[0]); p1.y = packbf(a1[1]);
    p3.x = packbf(a3[0]); p3.y = packbf(a3[1]);
    *(uint2*)(B1p + ob) = p1;
    *(uint2*)(B3p + ob) = p3;
    __half2 h01 = __floats2half2_rn(a2[0], a2[1]);
    *(u32*)(B2h + ob) = *(u32*)&h01;
}

// ---------------- fused attention v16: R15 + pixel-major ACC (one line per lane's atomics) ----------------
// Single variable vs the 161.3us R15 kernel: ACC layout [t][CI][HW] -> [t][HW][CI], so each
// PV lane's 16 channel-atomics land in ONE 64B line (was 16 partial lines; WRITE_SIZE 24.4MB
// for a 2.36MB array). Same addend sets per location -> same sums.
__global__ __launch_bounds__(512, 6) void attn_k(const u32* __restrict__ B1p,
                                                 const __half* __restrict__ B2h,
                                                 const u32* __restrict__ B3p,
                                                 float* __restrict__ ACCb)
{
    __shared__ __align__(16) char SM[53392];
    short*   Win  = (short*)SM;                // [32][32][16] bf16 plane (h then l) = 32768B
    __half2* Wp   = (__half2*)SM;              // PV plane [31][32][8] h2 = 31744B (over Win, dead)
    float*   Sc   = (float*)(SM + 32768);      // [4][441] = 7056B
    float*   Cb   = (float*)(SM + 39824);      // [8][320] = 10240B score bounce (stride CWS=20)
    int*     hist = (int*)(SM + 39824);        // radix overlay [4][256] = 4096B (Cb dead by then)
    float*   yiw  = (float*)(SM + 50064);      // [4][100] = 1600B
    int*     pab  = (int*)(SM + 51664);        // [4][100] = 1600B
    int*     ctl  = (int*)(SM + 53264);        // [4][8]   = 128B
    int tid = threadIdx.x;
    // XCD-aware decode (R10 proven: FETCH 15.1->6.3MB)
    int bid = blockIdx.x;
    int xcd = bid & 7, j = bid >> 3;           // j in [0,72)
    int tile = xcd * 18 + j % 18;              // [0,144)
    int t = j / 18;                            // [0,4)
    int qy = tile / 12, qx = tile - qy * 12;
    int qi = qy * 8, qj = qx * 8;

    const u32*    B1t = B1p + t * HW_ * 16;
    const __half* B2t = B2h + t * HW_ * 16;
    const u32*    B3t = B3p + t * HW_ * 16;

    int lane = tid & 63, wv = tid >> 6;           // wv in 0..7
    int nn = lane & 15, qsel = nn >> 3, pjn = nn & 7;
    int koff = (lane >> 4) * 8;

    // ---- stage h-plane: 32x32 window ----
    for (int pos = tid; pos < 1024; pos += 512) {
        int row = pos >> 5, col = pos & 31;
        int vr = min(max(qi - 10 + row, 0), 95);
        int vc = min(max(qj - 10 + col, 0), 95);
        const u32* src = B3t + (vr * 96 + vc) * 16;
        uint4 U0 = *(const uint4*)src,       U1 = *(const uint4*)(src + 4);
        uint4 U2 = *(const uint4*)(src + 8), U3 = *(const uint4*)(src + 12);
        uint4 A, B;
        A.x = __builtin_amdgcn_perm(U0.y, U0.x, HSEL);
        A.y = __builtin_amdgcn_perm(U0.w, U0.z, HSEL);
        A.z = __builtin_amdgcn_perm(U1.y, U1.x, HSEL);
        A.w = __builtin_amdgcn_perm(U1.w, U1.z, HSEL);
        B.x = __builtin_amdgcn_perm(U2.y, U2.x, HSEL);
        B.y = __builtin_amdgcn_perm(U2.w, U2.z, HSEL);
        B.z = __builtin_amdgcn_perm(U3.y, U3.x, HSEL);
        B.w = __builtin_amdgcn_perm(U3.w, U3.z, HSEL);
        *(uint4*)(Win + pos * 16)     = A;
        *(uint4*)(Win + pos * 16 + 8) = B;
    }
    __syncthreads();

    // ---- score phase A: Ah*Bh + Ah*Bl ----
#pragma unroll 1
    for (int ri = 0; ri < 2; ri++) {
        short8 Bh[4], Bl[4];
        int qiq = qi + 4 * ri, qjq = qj + 4 * qsel;
#pragma unroll
        for (int s = 0; s < 4; s++) {
            int kk0 = s * 32 + koff;
            int pi = kk0 >> 4, c0 = kk0 & 15;
            uint4 U0 = {0, 0, 0, 0}, U1 = {0, 0, 0, 0};
            if (pjn < 7 && pi < 7) {
                const u32* src = B1t + (min(qiq + pi, 95) * 96 + min(qjq + pjn, 95)) * 16 + c0;
                U0 = *(const uint4*)src;
                U1 = *(const uint4*)(src + 4);
            }
            union { uint4 u; short8 s8; } hc, lc;
            hc.u.x = __builtin_amdgcn_perm(U0.y, U0.x, HSEL);
            hc.u.y = __builtin_amdgcn_perm(U0.w, U0.z, HSEL);
            hc.u.z = __builtin_amdgcn_perm(U1.y, U1.x, HSEL);
            hc.u.w = __builtin_amdgcn_perm(U1.w, U1.z, HSEL);
            lc.u.x = __builtin_amdgcn_perm(U0.y, U0.x, LSEL);
            lc.u.y = __builtin_amdgcn_perm(U0.w, U0.z, LSEL);
            lc.u.z = __builtin_amdgcn_perm(U1.y, U1.x, LSEL);
            lc.u.w = __builtin_amdgcn_perm(U1.w, U1.z, LSEL);
            Bh[s] = hc.s8; Bl[s] = lc.s8;
        }
        float* Cw = Cb + wv * 320;
        for (int r = wv; r < 21; r += 8) {
            float psum = 0.f;
            int v = (lane >= 21) ? 1 : 0;
            int b = lane - v * 21;
#pragma unroll
            for (int st = 0; st < 2; st++) {
                float4v acc = {0.f, 0.f, 0.f, 0.f};
                __builtin_amdgcn_s_setprio(1);
#pragma unroll
                for (int s = 0; s < 4; s++) {
                    int arow = 4 * ri + r + 2 * s + (lane >> 5);
                    int aoff = (arow * 32 + st * 16 + nn) * 16 + ((lane >> 4) & 1) * 8;
                    short8 A = *(const short8*)(Win + aoff);
                    acc = __builtin_amdgcn_mfma_f32_16x16x32_bf16(A, Bh[s], acc, 0, 0, 0);
                    acc = __builtin_amdgcn_mfma_f32_16x16x32_bf16(A, Bl[s], acc, 0, 0, 0);
                }
                __builtin_amdgcn_s_setprio(0);
                *(float4v*)(Cw + nn * CWS + (lane >> 4) * 4) = acc;
                if (lane < 42) {
#pragma unroll
                    for (int pj = 0; pj < 7; pj++) {
                        int sp = b + 4 * v + pj;
                        if ((sp >> 4) == st) psum += Cw[(8 * v + pj) * CWS + (sp & 15)];
                    }
                }
            }
            if (lane < 42) Sc[(ri * 2 + v) * 441 + r * 21 + b] = psum;
        }
    }
    __syncthreads();

    // ---- stage l-plane (same packed source, L1-hot) ----
    for (int pos = tid; pos < 1024; pos += 512) {
        int row = pos >> 5, col = pos & 31;
        int vr = min(max(qi - 10 + row, 0), 95);
        int vc = min(max(qj - 10 + col, 0), 95);
        const u32* src = B3t + (vr * 96 + vc) * 16;
        uint4 U0 = *(const uint4*)src,       U1 = *(const uint4*)(src + 4);
        uint4 U2 = *(const uint4*)(src + 8), U3 = *(const uint4*)(src + 12);
        uint4 A, B;
        A.x = __builtin_amdgcn_perm(U0.y, U0.x, LSEL);
        A.y = __builtin_amdgcn_perm(U0.w, U0.z, LSEL);
        A.z = __builtin_amdgcn_perm(U1.y, U1.x, LSEL);
        A.w = __builtin_amdgcn_perm(U1.w, U1.z, LSEL);
        B.x = __builtin_amdgcn_perm(U2.y, U2.x, LSEL);
        B.y = __builtin_amdgcn_perm(U2.w, U2.z, LSEL);
        B.z = __builtin_amdgcn_perm(U3.y, U3.x, LSEL);
        B.w = __builtin_amdgcn_perm(U3.w, U3.z, LSEL);
        *(uint4*)(Win + pos * 16)     = A;
        *(uint4*)(Win + pos * 16 + 8) = B;
    }
    __syncthreads();

    // ---- score phase B: Sc += Al*Bh ----
#pragma unroll 1
    for (int ri = 0; ri < 2; ri++) {
        short8 Bh[4];
        int qiq = qi + 4 * ri, qjq = qj + 4 * qsel;
#pragma unroll
        for (int s = 0; s < 4; s++) {
            int kk0 = s * 32 + koff;
            int pi = kk0 >> 4, c0 = kk0 & 15;
            uint4 U0 = {0, 0, 0, 0}, U1 = {0, 0, 0, 0};
            if (pjn < 7 && pi < 7) {
                const u32* src = B1t + (min(qiq + pi, 95) * 96 + min(qjq + pjn, 95)) * 16 + c0;
                U0 = *(const uint4*)src;
                U1 = *(const uint4*)(src + 4);
            }
            union { uint4 u; short8 s8; } hc;
            hc.u.x = __builtin_amdgcn_perm(U0.y, U0.x, HSEL);
            hc.u.y = __builtin_amdgcn_perm(U0.w, U0.z, HSEL);
            hc.u.z = __builtin_amdgcn_perm(U1.y, U1.x, HSEL);
            hc.u.w = __builtin_amdgcn_perm(U1.w, U1.z, HSEL);
            Bh[s] = hc.s8;
        }
        float* Cw = Cb + wv * 320;
        for (int r = wv; r < 21; r += 8) {
            float psum = 0.f;
            int v = (lane >= 21) ? 1 : 0;
            int b = lane - v * 21;
#pragma unroll
            for (int st = 0; st < 2; st++) {
                float4v acc = {0.f, 0.f, 0.f, 0.f};
                __builtin_amdgcn_s_setprio(1);
#pragma unroll
                for (int s = 0; s < 4; s++) {
                    int arow = 4 * ri + r + 2 * s + (lane >> 5);
                    int aoff = (arow * 32 + st * 16 + nn) * 16 + ((lane >> 4) & 1) * 8;
                    short8 A = *(const short8*)(Win + aoff);
                    acc = __builtin_amdgcn_mfma_f32_16x16x32_bf16(A, Bh[s], acc, 0, 0, 0);
                }
                __builtin_amdgcn_s_setprio(0);
                *(float4v*)(Cw + nn * CWS + (lane >> 4) * 4) = acc;
                if (lane < 42) {
#pragma unroll
                    for (int pj = 0; pj < 7; pj++) {
                        int sp = b + 4 * v + pj;
                        if ((sp >> 4) == st) psum += Cw[(8 * v + pj) * CWS + (sp & 15)];
                    }
                }
            }
            if (lane < 42) Sc[(ri * 2 + v) * 441 + r * 21 + b] += psum;
        }
    }
    __syncthreads();     // Sc complete; Win dead from here

    // ---- tail: waves 0-3 wave-private radix/softmax || waves 4-7 stage PV plane ----
    int g = wv & 3;
    int ri2 = g >> 1, ci2 = g & 1;
    int qiq = qi + 4 * ri2, qjq = qj + 4 * ci2;
    int alo = max(0, 10 - qiq), ahi = min(20, 105 - qiq);
    int blo = max(0, 10 - qjq), bhi = min(20, 105 - qjq);
    u64 am0 = 0, am1 = 0;

    if (wv >= 4) {
        // stage PV f16 plane into Wp (over dead Win; 992*32B = 31744B)
        for (int pos = tid - 256; pos < 992; pos += 256) {
            int row = pos >> 5, col = pos & 31;
            int vr = min(max(qi - 10 + row, 0), 95);
            int vc = min(max(qj - 10 + col, 0), 95);
            const __half* src = B2t + (vr * 96 + vc) * 16;
            *(int4*)(Wp + pos * 8)     = *(const int4*)src;
            *(int4*)(Wp + pos * 8 + 4) = *(const int4*)(src + 8);
        }
    } else {
        // load keys (clip-remapped) into registers
        u32 kreg[7]; int ni = 0;
        u32 kmax = 0;
        for (int i = lane; i < NC_; i += 64) {
            int aa = i / 21, bb = i - aa * 21;
            int ae = min(max(aa, alo), ahi), be = min(max(bb, blo), bhi);
            u32 k = okey(Sc[g * 441 + ae * 21 + be]);
            kmax = max(kmax, k);
            kreg[ni++] = k;
        }
#pragma unroll
        for (int off = 1; off < 64; off <<= 1) kmax = max(kmax, (u32)__shfl_xor((int)kmax, off));

        // init own hist region + ctl (wave-private)
        {
            int4 zz = {0, 0, 0, 0};
            *(int4*)(hist + g * 256 + lane * 4) = zz;
            if (lane < 8) ctl[g * 8 + lane] = (lane == 1) ? K_ : 0;
        }
        asm volatile("s_waitcnt lgkmcnt(0)" ::: "memory");

        // wave-private 2-pass adaptive radix-256 (16-bit threshold; zero barriers)
#pragma unroll 1
        for (int ps = 3; ps >= 2; ps--) {
            u32 pref  = (u32)ctl[g * 8];
            int need0 = ctl[g * 8 + 1];
            for (int a = 0; a < ni; a++) {
                u32 k = kreg[a];
                if (ps == 3 || (k >> ((ps + 1) * 8)) == pref)
                    atomicAdd(&hist[g * 256 + ((k >> (ps * 8)) & 255)], 1);
            }
            asm volatile("s_waitcnt lgkmcnt(0)" ::: "memory");
            int4 hv = *(int4*)(hist + g * 256 + lane * 4);
            int local = hv.x + hv.y + hv.z + hv.w;
            int s = local;
#pragma unroll
            for (int off = 1; off < 64; off <<= 1) {
                int tt = __shfl_down(s, off);
                if (lane + off < 64) s += tt;
            }
            int c4 = s - local;
            int c3 = c4 + hv.w, c2 = c3 + hv.z, c1 = c2 + hv.y, c0 = s;
            int cums[5] = {c0, c1, c2, c3, c4};
            int hk[4] = {hv.x, hv.y, hv.z, hv.w};
#pragma unroll
            for (int k = 0; k < 4; k++) {
                if (cums[k] >= need0 && cums[k + 1] < need0) {
                    int newneed = need0 - cums[k + 1];
                    ctl[g * 8]     = (int)((pref << 8) | (u32)(lane * 4 + k));
                    ctl[g * 8 + 1] = newneed;
                    if (newneed == hk[k] || ps == 2) { ctl[g * 8 + 3] = 1; ctl[g * 8 + 2] = 8 * ps; }
                }
            }
            int4 zz = {0, 0, 0, 0};
            *(int4*)(hist + g * 256 + lane * 4) = zz;
            asm volatile("s_waitcnt lgkmcnt(0)" ::: "memory");
            if (ctl[g * 8 + 3]) break;        // wave-uniform LDS read
        }

        // selection + softmax + active-set ballots (proven pattern)
        {
            u32 theta = (u32)ctl[g * 8];
            int shift = ctl[g * 8 + 2];
            int need  = ctl[g * 8 + 1];
            int base  = K_ - need;
            int a2 = 0;
            for (int i = lane; i < NC_; i += 64) {
                u32 k = kreg[a2++];
                u32 hp = k >> shift;
                int slot = -1;
                if (hp > theta) slot = atomicAdd(&ctl[g * 8 + 4], 1);
                else if (hp == theta) {
                    int j2 = atomicAdd(&ctl[g * 8 + 5], 1);
                    if (j2 < need) slot = base + j2;
                }
                if (slot >= 0) {
                    int a = i / 21, b = i - a * 21;
                    int ae = min(max(a, alo), ahi), be = min(max(b, blo), bhi);
                    yiw[g * 100 + slot] = unokey(k);
                    pab[g * 100 + slot] = ((ae + 4 * ri2) << 8) | (be + 4 * ci2);
                }
            }
            asm volatile("s_waitcnt lgkmcnt(0)" ::: "memory");
            float m = unokey(kmax);
            float wa  = expf((yiw[g * 100 + lane] - m) * 10.f);
            float wb2 = (lane < 36) ? expf((yiw[g * 100 + 64 + lane] - m) * 10.f) : 0.f;
            float ssum = wa + wb2;
#pragma unroll
            for (int off = 1; off < 64; off <<= 1) ssum += __shfl_xor(ssum, off);
            float inv = 1.f / ssum;
            float wan = wa * inv, wbn = wb2 * inv;
            yiw[g * 100 + lane] = wan;
            if (lane < 36) yiw[g * 100 + 64 + lane] = wbn;
            am0 = __ballot(wan != 0.f);                    // active slots 0..63
            am1 = __ballot((lane < 36) && (wbn != 0.f));   // active slots 64..99
            asm volatile("s_waitcnt lgkmcnt(0)" ::: "memory");
        }
    }
    __syncthreads();     // single convergent rendezvous: Wp staged, yiw/pab final
    if (wv >= 4) return;

    // ---- PV: one wave per query from LDS Wp; pixel-major ACC (one 64B line per lane) ----
    if (lane < 49) {
        int rsel = lane & 1;
        int pi2 = lane / 7, pj2 = lane - pi2 * 7;
        __half2 z[8];
#pragma unroll
        for (int j2 = 0; j2 < 8; j2++) z[j2] = __float2half2_rn(0.f);
#pragma unroll 1
        for (int half = 0; half < 2; half++) {
            u64 mm = half ? am1 : am0;
            int kb = half ? 64 : 0;
            while (mm) {
                int k = kb + (__ffsll(mm) - 1);
                mm &= mm - 1;
                float y = yiw[g * 100 + k];      // LDS broadcast (wave-uniform addr)
                int pp = pab[g * 100 + k];
                int row = (pp >> 8) + pi2, col = (pp & 255) + pj2;
                const __half2* cell = Wp + (row * 32 + col) * 8;
                int4 A0 = *(const int4*)(cell + rsel * 4);
                int4 A1 = *(const int4*)(cell + 4 - rsel * 4);
                const __half2* pa  = (const __half2*)&A0;
                const __half2* pb2 = (const __half2*)&A1;
                __half2 yh = __float2half2_rn(y);
#pragma unroll
                for (int j2 = 0; j2 < 4; j2++) {
                    z[j2]     = __hfma2(pa[j2],  yh, z[j2]);
                    z[4 + j2] = __hfma2(pb2[j2], yh, z[4 + j2]);
                }
            }
        }
        int orow = min(qiq + pi2, 95), ocol = min(qjq + pj2, 95);
        float* dst = ACCb + (t * HW_ + orow * 96 + ocol) * CI_;   // pixel-major: 16 ch contiguous
        int c0 = rsel * 8, c1 = 8 - c0;
#pragma unroll
        for (int jh = 0; jh < 4; jh++) {
            atomicAdd(dst + c0 + 2 * jh,     __low2float(z[jh]));
            atomicAdd(dst + c0 + 2 * jh + 1, __high2float(z[jh]));
            atomicAdd(dst + c1 + 2 * jh,     __low2float(z[4 + jh]));
            atomicAdd(dst + c1 + 2 * jh + 1, __high2float(z[4 + jh]));
        }
    }
}

// ---------------- final: y = ACC/Z (Z analytic), conv1x1 + residual ----------------
__global__ __launch_bounds__(256) void out_k(const void* vid, const void* Ww, const void* Wb,
                                             const float* __restrict__ ACCb, void* out)
{
    __shared__ float w[1088];
    __shared__ int sflag;
    int tid = threadIdx.x;
    int isbf = detect_flag(vid, tid, &sflag);
    if (isbf) { for (int i = tid; i < 1088; i += 256) w[i] = (i < 1024) ? ldbf(Ww, i) : ldbf(Wb, i - 1024); }
    else      { for (int i = tid; i < 1088; i += 256) w[i] = (i < 1024) ? ldf (Ww, i) : ldf (Wb, i - 1024); }
    __syncthreads();

    int lane5 = tid & 31, oct = tid >> 5;
    int g0 = blockIdx.x * 32 + lane5;           // 1152*32 = 36864 exactly
    int t = g0 / HW_, pix = g0 - t * HW_;
    int pi = pix / 96, pj = pix - pi * 96;
    float invz = 1.f / (float)(cntdim(pi) * cntdim(pj));

    float y[CI_];
    int ab = (t * HW_ + pix) * CI_;             // pixel-major: lane's 16 ch contiguous (4xfloat4)
#pragma unroll
    for (int q = 0; q < 4; q++) {
        float4v v4 = *(const float4v*)(ACCb + ab + q * 4);
#pragma unroll
        for (int k = 0; k < 4; k++) y[q * 4 + k] = v4[k] * invz;
    }

    int vb = t * C_ * HW_ + pix;
#pragma unroll
    for (int co = oct * 8; co < oct * 8 + 8; co++) {
        float s = w[1024 + co];
#pragma unroll
        for (int ci = 0; ci < CI_; ci++) s += w[co * 16 + ci] * y[ci];
        int idx = vb + co * HW_;
        float vv = isbf ? ldbf(vid, idx) : ldf(vid, idx);
        float r = vv + s;
        if (isbf) ((bf16*)out)[idx] = __float2bfloat16(r);
        else      ((float*)out)[idx] = r;
    }
}

extern "C" void kernel_launch(void* const* d_in, const int* in_sizes, int n_in,
                              void* d_out, int out_size, void* d_ws, size_t ws_size,
                              hipStream_t stream)
{
    // ws byte layout: B1p @0, B2h @2359296, B3p @3538944, ACC @5898240
    char* ws = (char*)d_ws;
    u32*    B1p  = (u32*)ws;
    __half* B2h  = (__half*)(ws + 2359296);
    u32*    B3p  = (u32*)(ws + 3538944);
    float*  ACCb = (float*)(ws + 5898240);

    conv3_k<<<dim3(1152), dim3(256), 0, stream>>>(d_in[0], d_in[1], d_in[2], d_in[3], d_in[4],
                                                  d_in[5], d_in[6], B1p, B2h, B3p, ACCb);
    attn_k<<<dim3(576), dim3(512), 0, stream>>>(B1p, B2h, B3p, ACCb);
    out_k<<<dim3(1152), dim3(256), 0, stream>>>(d_in[0], d_in[7], d_in[8], ACCb, d_out);
}

// Round 17
// 162.544 us; speedup vs baseline: 1.3966x; 1.3966x over previous
//
#include <hip/hip_runtime.h>
#include <hip/hip_bf16.h>
#include <hip/hip_fp16.h>
#include <math.h>

typedef __hip_bfloat16 bf16;
typedef unsigned int u32;
typedef unsigned long long u64;
typedef __attribute__((ext_vector_type(8))) short short8;
typedef __attribute__((ext_vector_type(4))) float float4v;

#define T_   4
#define C_   64
#define H_   96
#define W_   96
#define CI_  16
#define HW_  9216
#define NC_  441
#define K_   100
#define HSEL 0x07060302u
#define LSEL 0x05040100u
#define CWS  20    // Cw stride in floats (R15 proven: bank conflicts 4.0M -> 1.67M)

__device__ __forceinline__ float ldbf(const void* p, int i) { return __bfloat162float(((const bf16*)p)[i]); }
__device__ __forceinline__ float ldf (const void* p, int i) { return ((const float*)p)[i]; }

__device__ __forceinline__ unsigned short f2bf(float x) {
    union { float f; u32 u; } a; a.f = x;
    u32 r = a.u + 0x7FFF + ((a.u >> 16) & 1);
    return (unsigned short)(r >> 16);
}
__device__ __forceinline__ float bf2f(unsigned short s) {
    union { u32 u; float f; } a; a.u = ((u32)s) << 16;
    return a.f;
}
__device__ __forceinline__ u32 packbf(float x) {
    unsigned short h = f2bf(x);
    unsigned short l = f2bf(x - bf2f(h));
    return ((u32)h << 16) | (u32)l;
}
__device__ __forceinline__ u32 okey(float f) {
    u32 u = __float_as_uint(f);
    return u ^ ((u & 0x80000000u) ? 0xFFFFFFFFu : 0x80000000u);
}
__device__ __forceinline__ float unokey(u32 k) {
    u32 u = (k & 0x80000000u) ? (k ^ 0x80000000u) : ~k;
    return __uint_as_float(u);
}
__device__ __forceinline__ int cntdim(int x) {
    int c = 0;
#pragma unroll
    for (int pp = 0; pp < 7; pp++) {
        int q = x - pp;
        c += (q >= 0 && q <= 92 && ((q & 3) == 0)) ? 1 : 0;
    }
    if (x == 95) c += 3;
    return c;
}

// per-block dtype vote (fp32 low-mantissa words decode to "insane" bf16 exponents)
__device__ __forceinline__ int detect_flag(const void* vid, int tid, int* sflag) {
    if (tid < 64) {
        unsigned short w = ((const unsigned short*)vid)[tid * 2];
        int e = (w >> 7) & 0xFF;
        int sane = ((e >= 100 && e <= 140) || ((w & 0x7FFF) == 0)) ? 1 : 0;
#pragma unroll
        for (int off = 1; off < 64; off <<= 1) sane += __shfl_xor(sane, off);
        if (tid == 0) *sflag = (sane >= 48) ? 1 : 0;
    }
    __syncthreads();
    return *sflag;
}

// ---------------- conv1x1 x3 + format conversion + ACC zero (R12 proven) ----------------
__global__ __launch_bounds__(256) void conv3_k(const void* vid, const void* gw, const void* gb,
                                               const void* tw, const void* tb, const void* pw,
                                               const void* pb,
                                               u32* __restrict__ B1p, __half* __restrict__ B2h,
                                               u32* __restrict__ B3p, float* __restrict__ ACCb)
{
    __shared__ __align__(16) float w[3120];
    __shared__ int sflag;
    int tid = threadIdx.x;
    int isbf = detect_flag(vid, tid, &sflag);
    for (int i = tid; i < 3120; i += 256) {
        float v;
        if (isbf) {
            if (i < 1024) v = ldbf(gw, i);
            else if (i < 2048) v = ldbf(tw, i - 1024);
            else if (i < 3072) v = ldbf(pw, i - 2048);
            else if (i < 3088) v = ldbf(gb, i - 3072);
            else if (i < 3104) v = ldbf(tb, i - 3088);
            else v = ldbf(pb, i - 3104);
        } else {
            if (i < 1024) v = ldf(gw, i);
            else if (i < 2048) v = ldf(tw, i - 1024);
            else if (i < 3072) v = ldf(pw, i - 2048);
            else if (i < 3088) v = ldf(gb, i - 3072);
            else if (i < 3104) v = ldf(tb, i - 3088);
            else v = ldf(pb, i - 3104);
        }
        int d;
        if (i < 3072) {
            int conv = i >> 10;               // 0,1,2
            int idx  = i & 1023;              // o*64 + c
            int o = idx >> 6, c = idx & 63;
            d = conv * 1024 + c * 16 + o;     // transposed: [conv][c][o]
        } else d = i;
        w[d] = v;
    }
    __syncthreads();

    {
        float2 z = {0.f, 0.f};
        *(float2*)(ACCb + (blockIdx.x * 256 + tid) * 2) = z;   // 1152*256*8B = 2359296 exactly
    }

    int lane32 = tid & 31, og = tid >> 5;      // og in [0,8), 2 channels each
    int g0 = blockIdx.x * 32 + lane32;         // 1152*32 = 36864 exactly
    int t = g0 / HW_, pix = g0 - t * HW_;

    float a1[2], a2[2], a3[2];
#pragma unroll
    for (int k = 0; k < 2; k++) {
        a1[k] = w[3072 + og * 2 + k];
        a2[k] = w[3088 + og * 2 + k];
        a3[k] = w[3104 + og * 2 + k];
    }
    int base = t * C_ * HW_ + pix;
#pragma unroll 16
    for (int c = 0; c < 64; c++) {
        float v = isbf ? ldbf(vid, base + c * HW_) : ldf(vid, base + c * HW_);
        float2 w1 = *(const float2*)&w[c * 16 + og * 2];
        float2 w2 = *(const float2*)&w[1024 + c * 16 + og * 2];
        float2 w3 = *(const float2*)&w[2048 + c * 16 + og * 2];
#pragma unroll
        for (int k = 0; k < 2; k++) {
            a1[k] += v * (&w1.x)[k];
            a2[k] += v * (&w2.x)[k];
            a3[k] += v * (&w3.x)[k];
        }
    }
    int ob = g0 * 16 + og * 2;
    uint2 p1, p3;
    p1.x = packbf(a1[0]); p1.y = packbf(a1[1]);
    p3.x = packbf(a3[0]); p3.y = packbf(a3[1]);
    *(uint2*)(B1p + ob) = p1;
    *(uint2*)(B3p + ob) = p3;
    __half2 h01 = __floats2half2_rn(a2[0], a2[1]);
    *(u32*)(B2h + ob) = *(u32*)&h01;
}

// ---------------- fused attention (R15 proven best, 161.3us): staged score + XCD banding
// + wave-private radix tail + setprio + CWS=20 bank-conflict-free score bounce;
// channel-major ACC atomics (R16's pixel-major regressed 2x: per-instruction line
// coverage 4 -> 49 lines, L2 atomic serialization). ----------------
__global__ __launch_bounds__(512, 6) void attn_k(const u32* __restrict__ B1p,
                                                 const __half* __restrict__ B2h,
                                                 const u32* __restrict__ B3p,
                                                 float* __restrict__ ACCb)
{
    __shared__ __align__(16) char SM[53392];
    short*   Win  = (short*)SM;                // [32][32][16] bf16 plane (h then l) = 32768B
    __half2* Wp   = (__half2*)SM;              // PV plane [31][32][8] h2 = 31744B (over Win, dead)
    float*   Sc   = (float*)(SM + 32768);      // [4][441] = 7056B
    float*   Cb   = (float*)(SM + 39824);      // [8][320] = 10240B score bounce (stride CWS=20)
    int*     hist = (int*)(SM + 39824);        // radix overlay [4][256] = 4096B (Cb dead by then)
    float*   yiw  = (float*)(SM + 50064);      // [4][100] = 1600B
    int*     pab  = (int*)(SM + 51664);        // [4][100] = 1600B
    int*     ctl  = (int*)(SM + 53264);        // [4][8]   = 128B
    int tid = threadIdx.x;
    // XCD-aware decode (R10 proven: FETCH 15.1->6.3MB)
    int bid = blockIdx.x;
    int xcd = bid & 7, j = bid >> 3;           // j in [0,72)
    int tile = xcd * 18 + j % 18;              // [0,144)
    int t = j / 18;                            // [0,4)
    int qy = tile / 12, qx = tile - qy * 12;
    int qi = qy * 8, qj = qx * 8;

    const u32*    B1t = B1p + t * HW_ * 16;
    const __half* B2t = B2h + t * HW_ * 16;
    const u32*    B3t = B3p + t * HW_ * 16;

    int lane = tid & 63, wv = tid >> 6;           // wv in 0..7
    int nn = lane & 15, qsel = nn >> 3, pjn = nn & 7;
    int koff = (lane >> 4) * 8;

    // ---- stage h-plane: 32x32 window ----
    for (int pos = tid; pos < 1024; pos += 512) {
        int row = pos >> 5, col = pos & 31;
        int vr = min(max(qi - 10 + row, 0), 95);
        int vc = min(max(qj - 10 + col, 0), 95);
        const u32* src = B3t + (vr * 96 + vc) * 16;
        uint4 U0 = *(const uint4*)src,       U1 = *(const uint4*)(src + 4);
        uint4 U2 = *(const uint4*)(src + 8), U3 = *(const uint4*)(src + 12);
        uint4 A, B;
        A.x = __builtin_amdgcn_perm(U0.y, U0.x, HSEL);
        A.y = __builtin_amdgcn_perm(U0.w, U0.z, HSEL);
        A.z = __builtin_amdgcn_perm(U1.y, U1.x, HSEL);
        A.w = __builtin_amdgcn_perm(U1.w, U1.z, HSEL);
        B.x = __builtin_amdgcn_perm(U2.y, U2.x, HSEL);
        B.y = __builtin_amdgcn_perm(U2.w, U2.z, HSEL);
        B.z = __builtin_amdgcn_perm(U3.y, U3.x, HSEL);
        B.w = __builtin_amdgcn_perm(U3.w, U3.z, HSEL);
        *(uint4*)(Win + pos * 16)     = A;
        *(uint4*)(Win + pos * 16 + 8) = B;
    }
    __syncthreads();

    // ---- score phase A: Ah*Bh + Ah*Bl ----
#pragma unroll 1
    for (int ri = 0; ri < 2; ri++) {
        short8 Bh[4], Bl[4];
        int qiq = qi + 4 * ri, qjq = qj + 4 * qsel;
#pragma unroll
        for (int s = 0; s < 4; s++) {
            int kk0 = s * 32 + koff;
            int pi = kk0 >> 4, c0 = kk0 & 15;
            uint4 U0 = {0, 0, 0, 0}, U1 = {0, 0, 0, 0};
            if (pjn < 7 && pi < 7) {
                const u32* src = B1t + (min(qiq + pi, 95) * 96 + min(qjq + pjn, 95)) * 16 + c0;
                U0 = *(const uint4*)src;
                U1 = *(const uint4*)(src + 4);
            }
            union { uint4 u; short8 s8; } hc, lc;
            hc.u.x = __builtin_amdgcn_perm(U0.y, U0.x, HSEL);
            hc.u.y = __builtin_amdgcn_perm(U0.w, U0.z, HSEL);
            hc.u.z = __builtin_amdgcn_perm(U1.y, U1.x, HSEL);
            hc.u.w = __builtin_amdgcn_perm(U1.w, U1.z, HSEL);
            lc.u.x = __builtin_amdgcn_perm(U0.y, U0.x, LSEL);
            lc.u.y = __builtin_amdgcn_perm(U0.w, U0.z, LSEL);
            lc.u.z = __builtin_amdgcn_perm(U1.y, U1.x, LSEL);
            lc.u.w = __builtin_amdgcn_perm(U1.w, U1.z, LSEL);
            Bh[s] = hc.s8; Bl[s] = lc.s8;
        }
        float* Cw = Cb + wv * 320;
        for (int r = wv; r < 21; r += 8) {
            float psum = 0.f;
            int v = (lane >= 21) ? 1 : 0;
            int b = lane - v * 21;
#pragma unroll
            for (int st = 0; st < 2; st++) {
                float4v acc = {0.f, 0.f, 0.f, 0.f};
                __builtin_amdgcn_s_setprio(1);
#pragma unroll
                for (int s = 0; s < 4; s++) {
                    int arow = 4 * ri + r + 2 * s + (lane >> 5);
                    int aoff = (arow * 32 + st * 16 + nn) * 16 + ((lane >> 4) & 1) * 8;
                    short8 A = *(const short8*)(Win + aoff);
                    acc = __builtin_amdgcn_mfma_f32_16x16x32_bf16(A, Bh[s], acc, 0, 0, 0);
                    acc = __builtin_amdgcn_mfma_f32_16x16x32_bf16(A, Bl[s], acc, 0, 0, 0);
                }
                __builtin_amdgcn_s_setprio(0);
                *(float4v*)(Cw + nn * CWS + (lane >> 4) * 4) = acc;
                if (lane < 42) {
#pragma unroll
                    for (int pj = 0; pj < 7; pj++) {
                        int sp = b + 4 * v + pj;
                        if ((sp >> 4) == st) psum += Cw[(8 * v + pj) * CWS + (sp & 15)];
                    }
                }
            }
            if (lane < 42) Sc[(ri * 2 + v) * 441 + r * 21 + b] = psum;
        }
    }
    __syncthreads();

    // ---- stage l-plane (same packed source, L1-hot) ----
    for (int pos = tid; pos < 1024; pos += 512) {
        int row = pos >> 5, col = pos & 31;
        int vr = min(max(qi - 10 + row, 0), 95);
        int vc = min(max(qj - 10 + col, 0), 95);
        const u32* src = B3t + (vr * 96 + vc) * 16;
        uint4 U0 = *(const uint4*)src,       U1 = *(const uint4*)(src + 4);
        uint4 U2 = *(const uint4*)(src + 8), U3 = *(const uint4*)(src + 12);
        uint4 A, B;
        A.x = __builtin_amdgcn_perm(U0.y, U0.x, LSEL);
        A.y = __builtin_amdgcn_perm(U0.w, U0.z, LSEL);
        A.z = __builtin_amdgcn_perm(U1.y, U1.x, LSEL);
        A.w = __builtin_amdgcn_perm(U1.w, U1.z, LSEL);
        B.x = __builtin_amdgcn_perm(U2.y, U2.x, LSEL);
        B.y = __builtin_amdgcn_perm(U2.w, U2.z, LSEL);
        B.z = __builtin_amdgcn_perm(U3.y, U3.x, LSEL);
        B.w = __builtin_amdgcn_perm(U3.w, U3.z, LSEL);
        *(uint4*)(Win + pos * 16)     = A;
        *(uint4*)(Win + pos * 16 + 8) = B;
    }
    __syncthreads();

    // ---- score phase B: Sc += Al*Bh ----
#pragma unroll 1
    for (int ri = 0; ri < 2; ri++) {
        short8 Bh[4];
        int qiq = qi + 4 * ri, qjq = qj + 4 * qsel;
#pragma unroll
        for (int s = 0; s < 4; s++) {
            int kk0 = s * 32 + koff;
            int pi = kk0 >> 4, c0 = kk0 & 15;
            uint4 U0 = {0, 0, 0, 0}, U1 = {0, 0, 0, 0};
            if (pjn < 7 && pi < 7) {
                const u32* src = B1t + (min(qiq + pi, 95) * 96 + min(qjq + pjn, 95)) * 16 + c0;
                U0 = *(const uint4*)src;
                U1 = *(const uint4*)(src + 4);
            }
            union { uint4 u; short8 s8; } hc;
            hc.u.x = __builtin_amdgcn_perm(U0.y, U0.x, HSEL);
            hc.u.y = __builtin_amdgcn_perm(U0.w, U0.z, HSEL);
            hc.u.z = __builtin_amdgcn_perm(U1.y, U1.x, HSEL);
            hc.u.w = __builtin_amdgcn_perm(U1.w, U1.z, HSEL);
            Bh[s] = hc.s8;
        }
        float* Cw = Cb + wv * 320;
        for (int r = wv; r < 21; r += 8) {
            float psum = 0.f;
            int v = (lane >= 21) ? 1 : 0;
            int b = lane - v * 21;
#pragma unroll
            for (int st = 0; st < 2; st++) {
                float4v acc = {0.f, 0.f, 0.f, 0.f};
                __builtin_amdgcn_s_setprio(1);
#pragma unroll
                for (int s = 0; s < 4; s++) {
                    int arow = 4 * ri + r + 2 * s + (lane >> 5);
                    int aoff = (arow * 32 + st * 16 + nn) * 16 + ((lane >> 4) & 1) * 8;
                    short8 A = *(const short8*)(Win + aoff);
                    acc = __builtin_amdgcn_mfma_f32_16x16x32_bf16(A, Bh[s], acc, 0, 0, 0);
                }
                __builtin_amdgcn_s_setprio(0);
                *(float4v*)(Cw + nn * CWS + (lane >> 4) * 4) = acc;
                if (lane < 42) {
#pragma unroll
                    for (int pj = 0; pj < 7; pj++) {
                        int sp = b + 4 * v + pj;
                        if ((sp >> 4) == st) psum += Cw[(8 * v + pj) * CWS + (sp & 15)];
                    }
                }
            }
            if (lane < 42) Sc[(ri * 2 + v) * 441 + r * 21 + b] += psum;
        }
    }
    __syncthreads();     // Sc complete; Win dead from here

    // ---- tail: waves 0-3 wave-private radix/softmax || waves 4-7 stage PV plane ----
    int g = wv & 3;
    int ri2 = g >> 1, ci2 = g & 1;
    int qiq = qi + 4 * ri2, qjq = qj + 4 * ci2;
    int alo = max(0, 10 - qiq), ahi = min(20, 105 - qiq);
    int blo = max(0, 10 - qjq), bhi = min(20, 105 - qjq);
    u64 am0 = 0, am1 = 0;

    if (wv >= 4) {
        // stage PV f16 plane into Wp (over dead Win; 992*32B = 31744B)
        for (int pos = tid - 256; pos < 992; pos += 256) {
            int row = pos >> 5, col = pos & 31;
            int vr = min(max(qi - 10 + row, 0), 95);
            int vc = min(max(qj - 10 + col, 0), 95);
            const __half* src = B2t + (vr * 96 + vc) * 16;
            *(int4*)(Wp + pos * 8)     = *(const int4*)src;
            *(int4*)(Wp + pos * 8 + 4) = *(const int4*)(src + 8);
        }
    } else {
        // load keys (clip-remapped) into registers
        u32 kreg[7]; int ni = 0;
        u32 kmax = 0;
        for (int i = lane; i < NC_; i += 64) {
            int aa = i / 21, bb = i - aa * 21;
            int ae = min(max(aa, alo), ahi), be = min(max(bb, blo), bhi);
            u32 k = okey(Sc[g * 441 + ae * 21 + be]);
            kmax = max(kmax, k);
            kreg[ni++] = k;
        }
#pragma unroll
        for (int off = 1; off < 64; off <<= 1) kmax = max(kmax, (u32)__shfl_xor((int)kmax, off));

        // init own hist region + ctl (wave-private)
        {
            int4 zz = {0, 0, 0, 0};
            *(int4*)(hist + g * 256 + lane * 4) = zz;
            if (lane < 8) ctl[g * 8 + lane] = (lane == 1) ? K_ : 0;
        }
        asm volatile("s_waitcnt lgkmcnt(0)" ::: "memory");

        // wave-private 2-pass adaptive radix-256 (16-bit threshold; zero barriers)
#pragma unroll 1
        for (int ps = 3; ps >= 2; ps--) {
            u32 pref  = (u32)ctl[g * 8];
            int need0 = ctl[g * 8 + 1];
            for (int a = 0; a < ni; a++) {
                u32 k = kreg[a];
                if (ps == 3 || (k >> ((ps + 1) * 8)) == pref)
                    atomicAdd(&hist[g * 256 + ((k >> (ps * 8)) & 255)], 1);
            }
            asm volatile("s_waitcnt lgkmcnt(0)" ::: "memory");
            int4 hv = *(int4*)(hist + g * 256 + lane * 4);
            int local = hv.x + hv.y + hv.z + hv.w;
            int s = local;
#pragma unroll
            for (int off = 1; off < 64; off <<= 1) {
                int tt = __shfl_down(s, off);
                if (lane + off < 64) s += tt;
            }
            int c4 = s - local;
            int c3 = c4 + hv.w, c2 = c3 + hv.z, c1 = c2 + hv.y, c0 = s;
            int cums[5] = {c0, c1, c2, c3, c4};
            int hk[4] = {hv.x, hv.y, hv.z, hv.w};
#pragma unroll
            for (int k = 0; k < 4; k++) {
                if (cums[k] >= need0 && cums[k + 1] < need0) {
                    int newneed = need0 - cums[k + 1];
                    ctl[g * 8]     = (int)((pref << 8) | (u32)(lane * 4 + k));
                    ctl[g * 8 + 1] = newneed;
                    if (newneed == hk[k] || ps == 2) { ctl[g * 8 + 3] = 1; ctl[g * 8 + 2] = 8 * ps; }
                }
            }
            int4 zz = {0, 0, 0, 0};
            *(int4*)(hist + g * 256 + lane * 4) = zz;
            asm volatile("s_waitcnt lgkmcnt(0)" ::: "memory");
            if (ctl[g * 8 + 3]) break;        // wave-uniform LDS read
        }

        // selection + softmax + active-set ballots (proven pattern)
        {
            u32 theta = (u32)ctl[g * 8];
            int shift = ctl[g * 8 + 2];
            int need  = ctl[g * 8 + 1];
            int base  = K_ - need;
            int a2 = 0;
            for (int i = lane; i < NC_; i += 64) {
                u32 k = kreg[a2++];
                u32 hp = k >> shift;
                int slot = -1;
                if (hp > theta) slot = atomicAdd(&ctl[g * 8 + 4], 1);
                else if (hp == theta) {
                    int j2 = atomicAdd(&ctl[g * 8 + 5], 1);
                    if (j2 < need) slot = base + j2;
                }
                if (slot >= 0) {
                    int a = i / 21, b = i - a * 21;
                    int ae = min(max(a, alo), ahi), be = min(max(b, blo), bhi);
                    yiw[g * 100 + slot] = unokey(k);
                    pab[g * 100 + slot] = ((ae + 4 * ri2) << 8) | (be + 4 * ci2);
                }
            }
            asm volatile("s_waitcnt lgkmcnt(0)" ::: "memory");
            float m = unokey(kmax);
            float wa  = expf((yiw[g * 100 + lane] - m) * 10.f);
            float wb2 = (lane < 36) ? expf((yiw[g * 100 + 64 + lane] - m) * 10.f) : 0.f;
            float ssum = wa + wb2;
#pragma unroll
            for (int off = 1; off < 64; off <<= 1) ssum += __shfl_xor(ssum, off);
            float inv = 1.f / ssum;
            float wan = wa * inv, wbn = wb2 * inv;
            yiw[g * 100 + lane] = wan;
            if (lane < 36) yiw[g * 100 + 64 + lane] = wbn;
            am0 = __ballot(wan != 0.f);                    // active slots 0..63
            am1 = __ballot((lane < 36) && (wbn != 0.f));   // active slots 64..99
            asm volatile("s_waitcnt lgkmcnt(0)" ::: "memory");
        }
    }
    __syncthreads();     // single convergent rendezvous: Wp staged, yiw/pab final
    if (wv >= 4) return;

    // ---- PV: one wave per query from LDS Wp; iterate ONLY surviving k's ----
    if (lane < 49) {
        int rsel = lane & 1;
        int pi2 = lane / 7, pj2 = lane - pi2 * 7;
        __half2 z[8];
#pragma unroll
        for (int j2 = 0; j2 < 8; j2++) z[j2] = __float2half2_rn(0.f);
#pragma unroll 1
        for (int half = 0; half < 2; half++) {
            u64 mm = half ? am1 : am0;
            int kb = half ? 64 : 0;
            while (mm) {
                int k = kb + (__ffsll(mm) - 1);
                mm &= mm - 1;
                float y = yiw[g * 100 + k];      // LDS broadcast (wave-uniform addr)
                int pp = pab[g * 100 + k];
                int row = (pp >> 8) + pi2, col = (pp & 255) + pj2;
                const __half2* cell = Wp + (row * 32 + col) * 8;
                int4 A0 = *(const int4*)(cell + rsel * 4);
                int4 A1 = *(const int4*)(cell + 4 - rsel * 4);
                const __half2* pa  = (const __half2*)&A0;
                const __half2* pb2 = (const __half2*)&A1;
                __half2 yh = __float2half2_rn(y);
#pragma unroll
                for (int j2 = 0; j2 < 4; j2++) {
                    z[j2]     = __hfma2(pa[j2],  yh, z[j2]);
                    z[4 + j2] = __hfma2(pb2[j2], yh, z[4 + j2]);
                }
            }
        }
        int orow = min(qiq + pi2, 95), ocol = min(qjq + pj2, 95);
        float* dst = ACCb + t * CI_ * HW_ + orow * 96 + ocol;
        int c0 = rsel * 8, c1 = 8 - c0;
#pragma unroll
        for (int jh = 0; jh < 4; jh++) {
            atomicAdd(dst + (c0 + 2 * jh) * HW_,     __low2float(z[jh]));
            atomicAdd(dst + (c0 + 2 * jh + 1) * HW_, __high2float(z[jh]));
            atomicAdd(dst + (c1 + 2 * jh) * HW_,     __low2float(z[4 + jh]));
            atomicAdd(dst + (c1 + 2 * jh + 1) * HW_, __high2float(z[4 + jh]));
        }
    }
}

// ---------------- final: y = ACC/Z (Z analytic), conv1x1 + residual ----------------
__global__ __launch_bounds__(256) void out_k(const void* vid, const void* Ww, const void* Wb,
                                             const float* __restrict__ ACCb, void* out)
{
    __shared__ float w[1088];
    __shared__ int sflag;
    int tid = threadIdx.x;
    int isbf = detect_flag(vid, tid, &sflag);
    if (isbf) { for (int i = tid; i < 1088; i += 256) w[i] = (i < 1024) ? ldbf(Ww, i) : ldbf(Wb, i - 1024); }
    else      { for (int i = tid; i < 1088; i += 256) w[i] = (i < 1024) ? ldf (Ww, i) : ldf (Wb, i - 1024); }
    __syncthreads();

    int lane5 = tid & 31, oct = tid >> 5;
    int g0 = blockIdx.x * 32 + lane5;           // 1152*32 = 36864 exactly
    int t = g0 / HW_, pix = g0 - t * HW_;
    int pi = pix / 96, pj = pix - pi * 96;
    float invz = 1.f / (float)(cntdim(pi) * cntdim(pj));

    float y[CI_];
    int ab = t * CI_ * HW_ + pix;
#pragma unroll
    for (int ci = 0; ci < CI_; ci++) y[ci] = ACCb[ab + ci * HW_] * invz;

    int vb = t * C_ * HW_ + pix;
#pragma unroll
    for (int co = oct * 8; co < oct * 8 + 8; co++) {
        float s = w[1024 + co];
#pragma unroll
        for (int ci = 0; ci < CI_; ci++) s += w[co * 16 + ci] * y[ci];
        int idx = vb + co * HW_;
        float vv = isbf ? ldbf(vid, idx) : ldf(vid, idx);
        float r = vv + s;
        if (isbf) ((bf16*)out)[idx] = __float2bfloat16(r);
        else      ((float*)out)[idx] = r;
    }
}

extern "C" void kernel_launch(void* const* d_in, const int* in_sizes, int n_in,
                              void* d_out, int out_size, void* d_ws, size_t ws_size,
                              hipStream_t stream)
{
    // ws byte layout: B1p @0, B2h @2359296, B3p @3538944, ACC @5898240
    char* ws = (char*)d_ws;
    u32*    B1p  = (u32*)ws;
    __half* B2h  = (__half*)(ws + 2359296);
    u32*    B3p  = (u32*)(ws + 3538944);
    float*  ACCb = (float*)(ws + 5898240);

    conv3_k<<<dim3(1152), dim3(256), 0, stream>>>(d_in[0], d_in[1], d_in[2], d_in[3], d_in[4],
                                                  d_in[5], d_in[6], B1p, B2h, B3p, ACCb);
    attn_k<<<dim3(576), dim3(512), 0, stream>>>(B1p, B2h, B3p, ACCb);
    out_k<<<dim3(1152), dim3(256), 0, stream>>>(d_in[0], d_in[7], d_in[8], ACCb, d_out);
}

// Round 18
// 161.165 us; speedup vs baseline: 1.4086x; 1.0086x over previous
//
#include <hip/hip_runtime.h>
#include <hip/hip_bf16.h>
#include <hip/hip_fp16.h>
#include <math.h>

typedef __hip_bfloat16 bf16;
typedef unsigned int u32;
typedef unsigned long long u64;
typedef __attribute__((ext_vector_type(8))) short short8;
typedef __attribute__((ext_vector_type(4))) float float4v;

#define T_   4
#define C_   64
#define H_   96
#define W_   96
#define CI_  16
#define HW_  9216
#define NC_  441
#define K_   100
#define HSEL 0x07060302u
#define LSEL 0x05040100u
#define CWS  20    // Cw stride in floats (R15 proven: bank conflicts 4.0M -> 1.67M)

__device__ __forceinline__ float ldbf(const void* p, int i) { return __bfloat162float(((const bf16*)p)[i]); }
__device__ __forceinline__ float ldf (const void* p, int i) { return ((const float*)p)[i]; }

__device__ __forceinline__ unsigned short f2bf(float x) {
    union { float f; u32 u; } a; a.f = x;
    u32 r = a.u + 0x7FFF + ((a.u >> 16) & 1);
    return (unsigned short)(r >> 16);
}
__device__ __forceinline__ float bf2f(unsigned short s) {
    union { u32 u; float f; } a; a.u = ((u32)s) << 16;
    return a.f;
}
__device__ __forceinline__ u32 packbf(float x) {
    unsigned short h = f2bf(x);
    unsigned short l = f2bf(x - bf2f(h));
    return ((u32)h << 16) | (u32)l;
}
__device__ __forceinline__ u32 okey(float f) {
    u32 u = __float_as_uint(f);
    return u ^ ((u & 0x80000000u) ? 0xFFFFFFFFu : 0x80000000u);
}
__device__ __forceinline__ float unokey(u32 k) {
    u32 u = (k & 0x80000000u) ? (k ^ 0x80000000u) : ~k;
    return __uint_as_float(u);
}
__device__ __forceinline__ int cntdim(int x) {
    int c = 0;
#pragma unroll
    for (int pp = 0; pp < 7; pp++) {
        int q = x - pp;
        c += (q >= 0 && q <= 92 && ((q & 3) == 0)) ? 1 : 0;
    }
    if (x == 95) c += 3;
    return c;
}

// per-block dtype vote (fp32 low-mantissa words decode to "insane" bf16 exponents)
__device__ __forceinline__ int detect_flag(const void* vid, int tid, int* sflag) {
    if (tid < 64) {
        unsigned short w = ((const unsigned short*)vid)[tid * 2];
        int e = (w >> 7) & 0xFF;
        int sane = ((e >= 100 && e <= 140) || ((w & 0x7FFF) == 0)) ? 1 : 0;
#pragma unroll
        for (int off = 1; off < 64; off <<= 1) sane += __shfl_xor(sane, off);
        if (tid == 0) *sflag = (sane >= 48) ? 1 : 0;
    }
    __syncthreads();
    return *sflag;
}

// ---------------- conv1x1 x3 + format conversion + ACC zero (R12 proven) ----------------
__global__ __launch_bounds__(256) void conv3_k(const void* vid, const void* gw, const void* gb,
                                               const void* tw, const void* tb, const void* pw,
                                               const void* pb,
                                               u32* __restrict__ B1p, __half* __restrict__ B2h,
                                               u32* __restrict__ B3p, float* __restrict__ ACCb)
{
    __shared__ __align__(16) float w[3120];
    __shared__ int sflag;
    int tid = threadIdx.x;
    int isbf = detect_flag(vid, tid, &sflag);
    for (int i = tid; i < 3120; i += 256) {
        float v;
        if (isbf) {
            if (i < 1024) v = ldbf(gw, i);
            else if (i < 2048) v = ldbf(tw, i - 1024);
            else if (i < 3072) v = ldbf(pw, i - 2048);
            else if (i < 3088) v = ldbf(gb, i - 3072);
            else if (i < 3104) v = ldbf(tb, i - 3088);
            else v = ldbf(pb, i - 3104);
        } else {
            if (i < 1024) v = ldf(gw, i);
            else if (i < 2048) v = ldf(tw, i - 1024);
            else if (i < 3072) v = ldf(pw, i - 2048);
            else if (i < 3088) v = ldf(gb, i - 3072);
            else if (i < 3104) v = ldf(tb, i - 3088);
            else v = ldf(pb, i - 3104);
        }
        int d;
        if (i < 3072) {
            int conv = i >> 10;               // 0,1,2
            int idx  = i & 1023;              // o*64 + c
            int o = idx >> 6, c = idx & 63;
            d = conv * 1024 + c * 16 + o;     // transposed: [conv][c][o]
        } else d = i;
        w[d] = v;
    }
    __syncthreads();

    {
        float2 z = {0.f, 0.f};
        *(float2*)(ACCb + (blockIdx.x * 256 + tid) * 2) = z;   // 1152*256*8B = 2359296 exactly
    }

    int lane32 = tid & 31, og = tid >> 5;      // og in [0,8), 2 channels each
    int g0 = blockIdx.x * 32 + lane32;         // 1152*32 = 36864 exactly
    int t = g0 / HW_, pix = g0 - t * HW_;

    float a1[2], a2[2], a3[2];
#pragma unroll
    for (int k = 0; k < 2; k++) {
        a1[k] = w[3072 + og * 2 + k];
        a2[k] = w[3088 + og * 2 + k];
        a3[k] = w[3104 + og * 2 + k];
    }
    int base = t * C_ * HW_ + pix;
#pragma unroll 16
    for (int c = 0; c < 64; c++) {
        float v = isbf ? ldbf(vid, base + c * HW_) : ldf(vid, base + c * HW_);
        float2 w1 = *(const float2*)&w[c * 16 + og * 2];
        float2 w2 = *(const float2*)&w[1024 + c * 16 + og * 2];
        float2 w3 = *(const float2*)&w[2048 + c * 16 + og * 2];
#pragma unroll
        for (int k = 0; k < 2; k++) {
            a1[k] += v * (&w1.x)[k];
            a2[k] += v * (&w2.x)[k];
            a3[k] += v * (&w3.x)[k];
        }
    }
    int ob = g0 * 16 + og * 2;
    uint2 p1, p3;
    p1.x = packbf(a1[0]); p1.y = packbf(a1[1]);
    p3.x = packbf(a3[0]); p3.y = packbf(a3[1]);
    *(uint2*)(B1p + ob) = p1;
    *(uint2*)(B3p + ob) = p3;
    __half2 h01 = __floats2half2_rn(a2[0], a2[1]);
    *(u32*)(B2h + ob) = *(u32*)&h01;
}

// ---------------- fused attention v18: R15/R17 + r-loop unroll (ILP across row iters) ----------------
// Single variable vs the proven 161-162us kernel: #pragma unroll on the per-wave r-row
// loops so iteration r+8's ds_read/MFMA chain issues under iteration r's scan/Sc-write.
// Bit-identical math (disjoint Sc addresses, independent iterations).
__global__ __launch_bounds__(512, 6) void attn_k(const u32* __restrict__ B1p,
                                                 const __half* __restrict__ B2h,
                                                 const u32* __restrict__ B3p,
                                                 float* __restrict__ ACCb)
{
    __shared__ __align__(16) char SM[53392];
    short*   Win  = (short*)SM;                // [32][32][16] bf16 plane (h then l) = 32768B
    __half2* Wp   = (__half2*)SM;              // PV plane [31][32][8] h2 = 31744B (over Win, dead)
    float*   Sc   = (float*)(SM + 32768);      // [4][441] = 7056B
    float*   Cb   = (float*)(SM + 39824);      // [8][320] = 10240B score bounce (stride CWS=20)
    int*     hist = (int*)(SM + 39824);        // radix overlay [4][256] = 4096B (Cb dead by then)
    float*   yiw  = (float*)(SM + 50064);      // [4][100] = 1600B
    int*     pab  = (int*)(SM + 51664);        // [4][100] = 1600B
    int*     ctl  = (int*)(SM + 53264);        // [4][8]   = 128B
    int tid = threadIdx.x;
    // XCD-aware decode (R10 proven: FETCH 15.1->6.3MB)
    int bid = blockIdx.x;
    int xcd = bid & 7, j = bid >> 3;           // j in [0,72)
    int tile = xcd * 18 + j % 18;              // [0,144)
    int t = j / 18;                            // [0,4)
    int qy = tile / 12, qx = tile - qy * 12;
    int qi = qy * 8, qj = qx * 8;

    const u32*    B1t = B1p + t * HW_ * 16;
    const __half* B2t = B2h + t * HW_ * 16;
    const u32*    B3t = B3p + t * HW_ * 16;

    int lane = tid & 63, wv = tid >> 6;           // wv in 0..7
    int nn = lane & 15, qsel = nn >> 3, pjn = nn & 7;
    int koff = (lane >> 4) * 8;

    // ---- stage h-plane: 32x32 window ----
    for (int pos = tid; pos < 1024; pos += 512) {
        int row = pos >> 5, col = pos & 31;
        int vr = min(max(qi - 10 + row, 0), 95);
        int vc = min(max(qj - 10 + col, 0), 95);
        const u32* src = B3t + (vr * 96 + vc) * 16;
        uint4 U0 = *(const uint4*)src,       U1 = *(const uint4*)(src + 4);
        uint4 U2 = *(const uint4*)(src + 8), U3 = *(const uint4*)(src + 12);
        uint4 A, B;
        A.x = __builtin_amdgcn_perm(U0.y, U0.x, HSEL);
        A.y = __builtin_amdgcn_perm(U0.w, U0.z, HSEL);
        A.z = __builtin_amdgcn_perm(U1.y, U1.x, HSEL);
        A.w = __builtin_amdgcn_perm(U1.w, U1.z, HSEL);
        B.x = __builtin_amdgcn_perm(U2.y, U2.x, HSEL);
        B.y = __builtin_amdgcn_perm(U2.w, U2.z, HSEL);
        B.z = __builtin_amdgcn_perm(U3.y, U3.x, HSEL);
        B.w = __builtin_amdgcn_perm(U3.w, U3.z, HSEL);
        *(uint4*)(Win + pos * 16)     = A;
        *(uint4*)(Win + pos * 16 + 8) = B;
    }
    __syncthreads();

    // ---- score phase A: Ah*Bh + Ah*Bl ----
#pragma unroll 1
    for (int ri = 0; ri < 2; ri++) {
        short8 Bh[4], Bl[4];
        int qiq = qi + 4 * ri, qjq = qj + 4 * qsel;
#pragma unroll
        for (int s = 0; s < 4; s++) {
            int kk0 = s * 32 + koff;
            int pi = kk0 >> 4, c0 = kk0 & 15;
            uint4 U0 = {0, 0, 0, 0}, U1 = {0, 0, 0, 0};
            if (pjn < 7 && pi < 7) {
                const u32* src = B1t + (min(qiq + pi, 95) * 96 + min(qjq + pjn, 95)) * 16 + c0;
                U0 = *(const uint4*)src;
                U1 = *(const uint4*)(src + 4);
            }
            union { uint4 u; short8 s8; } hc, lc;
            hc.u.x = __builtin_amdgcn_perm(U0.y, U0.x, HSEL);
            hc.u.y = __builtin_amdgcn_perm(U0.w, U0.z, HSEL);
            hc.u.z = __builtin_amdgcn_perm(U1.y, U1.x, HSEL);
            hc.u.w = __builtin_amdgcn_perm(U1.w, U1.z, HSEL);
            lc.u.x = __builtin_amdgcn_perm(U0.y, U0.x, LSEL);
            lc.u.y = __builtin_amdgcn_perm(U0.w, U0.z, LSEL);
            lc.u.z = __builtin_amdgcn_perm(U1.y, U1.x, LSEL);
            lc.u.w = __builtin_amdgcn_perm(U1.w, U1.z, LSEL);
            Bh[s] = hc.s8; Bl[s] = lc.s8;
        }
        float* Cw = Cb + wv * 320;
#pragma unroll
        for (int r = wv; r < 21; r += 8) {
            float psum = 0.f;
            int v = (lane >= 21) ? 1 : 0;
            int b = lane - v * 21;
#pragma unroll
            for (int st = 0; st < 2; st++) {
                float4v acc = {0.f, 0.f, 0.f, 0.f};
                __builtin_amdgcn_s_setprio(1);
#pragma unroll
                for (int s = 0; s < 4; s++) {
                    int arow = 4 * ri + r + 2 * s + (lane >> 5);
                    int aoff = (arow * 32 + st * 16 + nn) * 16 + ((lane >> 4) & 1) * 8;
                    short8 A = *(const short8*)(Win + aoff);
                    acc = __builtin_amdgcn_mfma_f32_16x16x32_bf16(A, Bh[s], acc, 0, 0, 0);
                    acc = __builtin_amdgcn_mfma_f32_16x16x32_bf16(A, Bl[s], acc, 0, 0, 0);
                }
                __builtin_amdgcn_s_setprio(0);
                *(float4v*)(Cw + nn * CWS + (lane >> 4) * 4) = acc;
                if (lane < 42) {
#pragma unroll
                    for (int pj = 0; pj < 7; pj++) {
                        int sp = b + 4 * v + pj;
                        if ((sp >> 4) == st) psum += Cw[(8 * v + pj) * CWS + (sp & 15)];
                    }
                }
            }
            if (lane < 42) Sc[(ri * 2 + v) * 441 + r * 21 + b] = psum;
        }
    }
    __syncthreads();

    // ---- stage l-plane (same packed source, L1-hot) ----
    for (int pos = tid; pos < 1024; pos += 512) {
        int row = pos >> 5, col = pos & 31;
        int vr = min(max(qi - 10 + row, 0), 95);
        int vc = min(max(qj - 10 + col, 0), 95);
        const u32* src = B3t + (vr * 96 + vc) * 16;
        uint4 U0 = *(const uint4*)src,       U1 = *(const uint4*)(src + 4);
        uint4 U2 = *(const uint4*)(src + 8), U3 = *(const uint4*)(src + 12);
        uint4 A, B;
        A.x = __builtin_amdgcn_perm(U0.y, U0.x, LSEL);
        A.y = __builtin_amdgcn_perm(U0.w, U0.z, LSEL);
        A.z = __builtin_amdgcn_perm(U1.y, U1.x, LSEL);
        A.w = __builtin_amdgcn_perm(U1.w, U1.z, LSEL);
        B.x = __builtin_amdgcn_perm(U2.y, U2.x, LSEL);
        B.y = __builtin_amdgcn_perm(U2.w, U2.z, LSEL);
        B.z = __builtin_amdgcn_perm(U3.y, U3.x, LSEL);
        B.w = __builtin_amdgcn_perm(U3.w, U3.z, LSEL);
        *(uint4*)(Win + pos * 16)     = A;
        *(uint4*)(Win + pos * 16 + 8) = B;
    }
    __syncthreads();

    // ---- score phase B: Sc += Al*Bh ----
#pragma unroll 1
    for (int ri = 0; ri < 2; ri++) {
        short8 Bh[4];
        int qiq = qi + 4 * ri, qjq = qj + 4 * qsel;
#pragma unroll
        for (int s = 0; s < 4; s++) {
            int kk0 = s * 32 + koff;
            int pi = kk0 >> 4, c0 = kk0 & 15;
            uint4 U0 = {0, 0, 0, 0}, U1 = {0, 0, 0, 0};
            if (pjn < 7 && pi < 7) {
                const u32* src = B1t + (min(qiq + pi, 95) * 96 + min(qjq + pjn, 95)) * 16 + c0;
                U0 = *(const uint4*)src;
                U1 = *(const uint4*)(src + 4);
            }
            union { uint4 u; short8 s8; } hc;
            hc.u.x = __builtin_amdgcn_perm(U0.y, U0.x, HSEL);
            hc.u.y = __builtin_amdgcn_perm(U0.w, U0.z, HSEL);
            hc.u.z = __builtin_amdgcn_perm(U1.y, U1.x, HSEL);
            hc.u.w = __builtin_amdgcn_perm(U1.w, U1.z, HSEL);
            Bh[s] = hc.s8;
        }
        float* Cw = Cb + wv * 320;
#pragma unroll
        for (int r = wv; r < 21; r += 8) {
            float psum = 0.f;
            int v = (lane >= 21) ? 1 : 0;
            int b = lane - v * 21;
#pragma unroll
            for (int st = 0; st < 2; st++) {
                float4v acc = {0.f, 0.f, 0.f, 0.f};
                __builtin_amdgcn_s_setprio(1);
#pragma unroll
                for (int s = 0; s < 4; s++) {
                    int arow = 4 * ri + r + 2 * s + (lane >> 5);
                    int aoff = (arow * 32 + st * 16 + nn) * 16 + ((lane >> 4) & 1) * 8;
                    short8 A = *(const short8*)(Win + aoff);
                    acc = __builtin_amdgcn_mfma_f32_16x16x32_bf16(A, Bh[s], acc, 0, 0, 0);
                }
                __builtin_amdgcn_s_setprio(0);
                *(float4v*)(Cw + nn * CWS + (lane >> 4) * 4) = acc;
                if (lane < 42) {
#pragma unroll
                    for (int pj = 0; pj < 7; pj++) {
                        int sp = b + 4 * v + pj;
                        if ((sp >> 4) == st) psum += Cw[(8 * v + pj) * CWS + (sp & 15)];
                    }
                }
            }
            if (lane < 42) Sc[(ri * 2 + v) * 441 + r * 21 + b] += psum;
        }
    }
    __syncthreads();     // Sc complete; Win dead from here

    // ---- tail: waves 0-3 wave-private radix/softmax || waves 4-7 stage PV plane ----
    int g = wv & 3;
    int ri2 = g >> 1, ci2 = g & 1;
    int qiq = qi + 4 * ri2, qjq = qj + 4 * ci2;
    int alo = max(0, 10 - qiq), ahi = min(20, 105 - qiq);
    int blo = max(0, 10 - qjq), bhi = min(20, 105 - qjq);
    u64 am0 = 0, am1 = 0;

    if (wv >= 4) {
        // stage PV f16 plane into Wp (over dead Win; 992*32B = 31744B)
        for (int pos = tid - 256; pos < 992; pos += 256) {
            int row = pos >> 5, col = pos & 31;
            int vr = min(max(qi - 10 + row, 0), 95);
            int vc = min(max(qj - 10 + col, 0), 95);
            const __half* src = B2t + (vr * 96 + vc) * 16;
            *(int4*)(Wp + pos * 8)     = *(const int4*)src;
            *(int4*)(Wp + pos * 8 + 4) = *(const int4*)(src + 8);
        }
    } else {
        // load keys (clip-remapped) into registers
        u32 kreg[7]; int ni = 0;
        u32 kmax = 0;
        for (int i = lane; i < NC_; i += 64) {
            int aa = i / 21, bb = i - aa * 21;
            int ae = min(max(aa, alo), ahi), be = min(max(bb, blo), bhi);
            u32 k = okey(Sc[g * 441 + ae * 21 + be]);
            kmax = max(kmax, k);
            kreg[ni++] = k;
        }
#pragma unroll
        for (int off = 1; off < 64; off <<= 1) kmax = max(kmax, (u32)__shfl_xor((int)kmax, off));

        // init own hist region + ctl (wave-private)
        {
            int4 zz = {0, 0, 0, 0};
            *(int4*)(hist + g * 256 + lane * 4) = zz;
            if (lane < 8) ctl[g * 8 + lane] = (lane == 1) ? K_ : 0;
        }
        asm volatile("s_waitcnt lgkmcnt(0)" ::: "memory");

        // wave-private 2-pass adaptive radix-256 (16-bit threshold; zero barriers)
#pragma unroll 1
        for (int ps = 3; ps >= 2; ps--) {
            u32 pref  = (u32)ctl[g * 8];
            int need0 = ctl[g * 8 + 1];
            for (int a = 0; a < ni; a++) {
                u32 k = kreg[a];
                if (ps == 3 || (k >> ((ps + 1) * 8)) == pref)
                    atomicAdd(&hist[g * 256 + ((k >> (ps * 8)) & 255)], 1);
            }
            asm volatile("s_waitcnt lgkmcnt(0)" ::: "memory");
            int4 hv = *(int4*)(hist + g * 256 + lane * 4);
            int local = hv.x + hv.y + hv.z + hv.w;
            int s = local;
#pragma unroll
            for (int off = 1; off < 64; off <<= 1) {
                int tt = __shfl_down(s, off);
                if (lane + off < 64) s += tt;
            }
            int c4 = s - local;
            int c3 = c4 + hv.w, c2 = c3 + hv.z, c1 = c2 + hv.y, c0 = s;
            int cums[5] = {c0, c1, c2, c3, c4};
            int hk[4] = {hv.x, hv.y, hv.z, hv.w};
#pragma unroll
            for (int k = 0; k < 4; k++) {
                if (cums[k] >= need0 && cums[k + 1] < need0) {
                    int newneed = need0 - cums[k + 1];
                    ctl[g * 8]     = (int)((pref << 8) | (u32)(lane * 4 + k));
                    ctl[g * 8 + 1] = newneed;
                    if (newneed == hk[k] || ps == 2) { ctl[g * 8 + 3] = 1; ctl[g * 8 + 2] = 8 * ps; }
                }
            }
            int4 zz = {0, 0, 0, 0};
            *(int4*)(hist + g * 256 + lane * 4) = zz;
            asm volatile("s_waitcnt lgkmcnt(0)" ::: "memory");
            if (ctl[g * 8 + 3]) break;        // wave-uniform LDS read
        }

        // selection + softmax + active-set ballots (proven pattern)
        {
            u32 theta = (u32)ctl[g * 8];
            int shift = ctl[g * 8 + 2];
            int need  = ctl[g * 8 + 1];
            int base  = K_ - need;
            int a2 = 0;
            for (int i = lane; i < NC_; i += 64) {
                u32 k = kreg[a2++];
                u32 hp = k >> shift;
                int slot = -1;
                if (hp > theta) slot = atomicAdd(&ctl[g * 8 + 4], 1);
                else if (hp == theta) {
                    int j2 = atomicAdd(&ctl[g * 8 + 5], 1);
                    if (j2 < need) slot = base + j2;
                }
                if (slot >= 0) {
                    int a = i / 21, b = i - a * 21;
                    int ae = min(max(a, alo), ahi), be = min(max(b, blo), bhi);
                    yiw[g * 100 + slot] = unokey(k);
                    pab[g * 100 + slot] = ((ae + 4 * ri2) << 8) | (be + 4 * ci2);
                }
            }
            asm volatile("s_waitcnt lgkmcnt(0)" ::: "memory");
            float m = unokey(kmax);
            float wa  = expf((yiw[g * 100 + lane] - m) * 10.f);
            float wb2 = (lane < 36) ? expf((yiw[g * 100 + 64 + lane] - m) * 10.f) : 0.f;
            float ssum = wa + wb2;
#pragma unroll
            for (int off = 1; off < 64; off <<= 1) ssum += __shfl_xor(ssum, off);
            float inv = 1.f / ssum;
            float wan = wa * inv, wbn = wb2 * inv;
            yiw[g * 100 + lane] = wan;
            if (lane < 36) yiw[g * 100 + 64 + lane] = wbn;
            am0 = __ballot(wan != 0.f);                    // active slots 0..63
            am1 = __ballot((lane < 36) && (wbn != 0.f));   // active slots 64..99
            asm volatile("s_waitcnt lgkmcnt(0)" ::: "memory");
        }
    }
    __syncthreads();     // single convergent rendezvous: Wp staged, yiw/pab final
    if (wv >= 4) return;

    // ---- PV: one wave per query from LDS Wp; iterate ONLY surviving k's ----
    if (lane < 49) {
        int rsel = lane & 1;
        int pi2 = lane / 7, pj2 = lane - pi2 * 7;
        __half2 z[8];
#pragma unroll
        for (int j2 = 0; j2 < 8; j2++) z[j2] = __float2half2_rn(0.f);
#pragma unroll 1
        for (int half = 0; half < 2; half++) {
            u64 mm = half ? am1 : am0;
            int kb = half ? 64 : 0;
            while (mm) {
                int k = kb + (__ffsll(mm) - 1);
                mm &= mm - 1;
                float y = yiw[g * 100 + k];      // LDS broadcast (wave-uniform addr)
                int pp = pab[g * 100 + k];
                int row = (pp >> 8) + pi2, col = (pp & 255) + pj2;
                const __half2* cell = Wp + (row * 32 + col) * 8;
                int4 A0 = *(const int4*)(cell + rsel * 4);
                int4 A1 = *(const int4*)(cell + 4 - rsel * 4);
                const __half2* pa  = (const __half2*)&A0;
                const __half2* pb2 = (const __half2*)&A1;
                __half2 yh = __float2half2_rn(y);
#pragma unroll
                for (int j2 = 0; j2 < 4; j2++) {
                    z[j2]     = __hfma2(pa[j2],  yh, z[j2]);
                    z[4 + j2] = __hfma2(pb2[j2], yh, z[4 + j2]);
                }
            }
        }
        int orow = min(qiq + pi2, 95), ocol = min(qjq + pj2, 95);
        float* dst = ACCb + t * CI_ * HW_ + orow * 96 + ocol;
        int c0 = rsel * 8, c1 = 8 - c0;
#pragma unroll
        for (int jh = 0; jh < 4; jh++) {
            atomicAdd(dst + (c0 + 2 * jh) * HW_,     __low2float(z[jh]));
            atomicAdd(dst + (c0 + 2 * jh + 1) * HW_, __high2float(z[jh]));
            atomicAdd(dst + (c1 + 2 * jh) * HW_,     __low2float(z[4 + jh]));
            atomicAdd(dst + (c1 + 2 * jh + 1) * HW_, __high2float(z[4 + jh]));
        }
    }
}

// ---------------- final: y = ACC/Z (Z analytic), conv1x1 + residual ----------------
__global__ __launch_bounds__(256) void out_k(const void* vid, const void* Ww, const void* Wb,
                                             const float* __restrict__ ACCb, void* out)
{
    __shared__ float w[1088];
    __shared__ int sflag;
    int tid = threadIdx.x;
    int isbf = detect_flag(vid, tid, &sflag);
    if (isbf) { for (int i = tid; i < 1088; i += 256) w[i] = (i < 1024) ? ldbf(Ww, i) : ldbf(Wb, i - 1024); }
    else      { for (int i = tid; i < 1088; i += 256) w[i] = (i < 1024) ? ldf (Ww, i) : ldf (Wb, i - 1024); }
    __syncthreads();

    int lane5 = tid & 31, oct = tid >> 5;
    int g0 = blockIdx.x * 32 + lane5;           // 1152*32 = 36864 exactly
    int t = g0 / HW_, pix = g0 - t * HW_;
    int pi = pix / 96, pj = pix - pi * 96;
    float invz = 1.f / (float)(cntdim(pi) * cntdim(pj));

    float y[CI_];
    int ab = t * CI_ * HW_ + pix;
#pragma unroll
    for (int ci = 0; ci < CI_; ci++) y[ci] = ACCb[ab + ci * HW_] * invz;

    int vb = t * C_ * HW_ + pix;
#pragma unroll
    for (int co = oct * 8; co < oct * 8 + 8; co++) {
        float s = w[1024 + co];
#pragma unroll
        for (int ci = 0; ci < CI_; ci++) s += w[co * 16 + ci] * y[ci];
        int idx = vb + co * HW_;
        float vv = isbf ? ldbf(vid, idx) : ldf(vid, idx);
        float r = vv + s;
        if (isbf) ((bf16*)out)[idx] = __float2bfloat16(r);
        else      ((float*)out)[idx] = r;
    }
}

extern "C" void kernel_launch(void* const* d_in, const int* in_sizes, int n_in,
                              void* d_out, int out_size, void* d_ws, size_t ws_size,
                              hipStream_t stream)
{
    // ws byte layout: B1p @0, B2h @2359296, B3p @3538944, ACC @5898240
    char* ws = (char*)d_ws;
    u32*    B1p  = (u32*)ws;
    __half* B2h  = (__half*)(ws + 2359296);
    u32*    B3p  = (u32*)(ws + 3538944);
    float*  ACCb = (float*)(ws + 5898240);

    conv3_k<<<dim3(1152), dim3(256), 0, stream>>>(d_in[0], d_in[1], d_in[2], d_in[3], d_in[4],
                                                  d_in[5], d_in[6], B1p, B2h, B3p, ACCb);
    attn_k<<<dim3(576), dim3(512), 0, stream>>>(B1p, B2h, B3p, ACCb);
    out_k<<<dim3(1152), dim3(256), 0, stream>>>(d_in[0], d_in[7], d_in[8], ACCb, d_out);
}